// Round 11
// baseline (116.628 us; speedup 1.0000x reference)
//
#include <hip/hip_runtime.h>

#define DD 128
#define CAP 12288          // per-bucket slot capacity (mean 8163, +45 sigma)
#define WP 136             // padded LDS stride for staged W (16B-aligned, 2-way banks)

typedef __attribute__((ext_vector_type(8))) short bf16x8;
typedef __attribute__((ext_vector_type(4))) float f32x4;

__device__ inline unsigned short f2b(float f) {
    unsigned int u = __float_as_uint(f);
    u += 0x7fffu + ((u >> 16) & 1u);   // RNE
    return (unsigned short)(u >> 16);
}

// acc += bf16x8(v) * s
__device__ inline void bacc16f(float4& a, float4& b, uint4 v, float s) {
    a.x += __uint_as_float(v.x << 16) * s;
    a.y += __uint_as_float(v.x & 0xffff0000u) * s;
    a.z += __uint_as_float(v.y << 16) * s;
    a.w += __uint_as_float(v.y & 0xffff0000u) * s;
    b.x += __uint_as_float(v.z << 16) * s;
    b.y += __uint_as_float(v.z & 0xffff0000u) * s;
    b.z += __uint_as_float(v.w << 16) * s;
    b.w += __uint_as_float(v.w & 0xffff0000u) * s;
}

// ---- FUSED A: gemm role (blocks 0..ngA-1) + binA role (rest) ----
// gemm: stages W -> LDS bf16 [c][k] per block (W is LLC-hot), then R7-verbatim
// MFMA body reading b-fragments from LDS. binA: R10-verbatim int4 two-pass
// binning; cur starts at 0 (memset), absolute base = t*CAP + reservation.
union UA {
    struct { int hist[256]; int base[256]; int curs[256]; } a;
    unsigned short wlds[DD * WP];
};

__global__ __launch_bounds__(256) void k_fA(const int* __restrict__ src,
                                            const int* __restrict__ dst, int E,
                                            int chunk, int nbuck,
                                            int* __restrict__ cur,
                                            int* __restrict__ binned,
                                            const float* __restrict__ x,
                                            const float* __restrict__ W,
                                            unsigned short* __restrict__ hs,
                                            int n, int ngA) {
    __shared__ UA u;
    const int t = threadIdx.x;
    if ((int)blockIdx.x >= ngA) {
        const int e0 = (blockIdx.x - ngA) * chunk;
        const int e1 = min(e0 + chunk, E);   // span is a multiple of 4 (E%4==0)

        u.a.hist[t] = 0; u.a.curs[t] = 0;
        __syncthreads();
        for (int e = e0 + t * 4; e < e1; e += 1024) {
            int4 d4 = *(const int4*)(dst + e);
            atomicAdd(&u.a.hist[d4.x >> 9], 1);
            atomicAdd(&u.a.hist[d4.y >> 9], 1);
            atomicAdd(&u.a.hist[d4.z >> 9], 1);
            atomicAdd(&u.a.hist[d4.w >> 9], 1);
        }
        __syncthreads();
        if (t < nbuck && u.a.hist[t] > 0)
            u.a.base[t] = t * CAP + atomicAdd(&cur[t], u.a.hist[t]);
        __syncthreads();
        for (int e = e0 + t * 4; e < e1; e += 1024) {
            int4 d4 = *(const int4*)(dst + e);
            int4 s4 = *(const int4*)(src + e);
            {
                int b = d4.x >> 9, p = atomicAdd(&u.a.curs[b], 1), idx = u.a.base[b] + p;
                if (idx < (b + 1) * CAP) binned[idx] = (s4.x << 9) | (d4.x & 511);
            }
            {
                int b = d4.y >> 9, p = atomicAdd(&u.a.curs[b], 1), idx = u.a.base[b] + p;
                if (idx < (b + 1) * CAP) binned[idx] = (s4.y << 9) | (d4.y & 511);
            }
            {
                int b = d4.z >> 9, p = atomicAdd(&u.a.curs[b], 1), idx = u.a.base[b] + p;
                if (idx < (b + 1) * CAP) binned[idx] = (s4.z << 9) | (d4.z & 511);
            }
            {
                int b = d4.w >> 9, p = atomicAdd(&u.a.curs[b], 1), idx = u.a.base[b] + p;
                if (idx < (b + 1) * CAP) binned[idx] = (s4.w << 9) | (d4.w & 511);
            }
        }
        return;
    }

    // ================= gemm role (raw, no dinv) =================
    // stage W[k][c] fp32 -> LDS bf16 [c][k] (padded stride WP)
    for (int i = t; i < DD * DD; i += 256) {
        int k = i >> 7, c = i & 127;
        u.wlds[c * WP + k] = f2b(W[i]);
    }
    __syncthreads();

    const int wave = t >> 6, lane = t & 63;
    const int rowbase = blockIdx.x * 256 + wave * 64;
    const int l15 = lane & 15, l4 = lane >> 4;

    bf16x8 a[4][4];
    #pragma unroll
    for (int rb = 0; rb < 4; ++rb) {
        int r = rowbase + rb * 16 + l15;
        int rc = min(r, n - 1);
        const float* xr = x + (size_t)rc * DD;
        #pragma unroll
        for (int kc = 0; kc < 4; ++kc) {
            int k0 = kc * 32 + l4 * 8;
            float4 f0 = *(const float4*)(xr + k0);
            float4 f1 = *(const float4*)(xr + k0 + 4);
            bf16x8 fr;
            fr[0] = (short)f2b(f0.x); fr[1] = (short)f2b(f0.y);
            fr[2] = (short)f2b(f0.z); fr[3] = (short)f2b(f0.w);
            fr[4] = (short)f2b(f1.x); fr[5] = (short)f2b(f1.y);
            fr[6] = (short)f2b(f1.z); fr[7] = (short)f2b(f1.w);
            a[rb][kc] = fr;
        }
    }

    #pragma unroll
    for (int cb = 0; cb < 8; ++cb) {
        int c0 = cb * 16;
        f32x4 acc[4] = {};
        #pragma unroll
        for (int kc = 0; kc < 4; ++kc) {
            bf16x8 bfrag = *(const bf16x8*)(&u.wlds[(c0 + l15) * WP + kc * 32 + l4 * 8]);
            #pragma unroll
            for (int rb = 0; rb < 4; ++rb)
                acc[rb] = __builtin_amdgcn_mfma_f32_16x16x32_bf16(a[rb][kc], bfrag, acc[rb], 0, 0, 0);
        }
        #pragma unroll
        for (int rb = 0; rb < 4; ++rb) {
            int r0 = rowbase + rb * 16 + l4 * 4;
            #pragma unroll
            for (int vv = 0; vv < 4; ++vv) {
                int r = r0 + vv;
                if (r < n)
                    hs[(size_t)r * DD + c0 + l15] = f2b(acc[rb][vv]);
            }
        }
    }
}

// ---- FUSED B: binB role (blocks 0..nbuck-1) + gemm role (rest) ----
// binB: R10-verbatim (int4 hist, shfl scan, LDS sort, dense int4 writeback);
// cb read directly from cur (counts). gemm: upgraded to 4-row fragments,
// 512 rows/block (8 waves x 64 rows), W staged in LDS (union with sorted).
union UB {
    int sorted[CAP];
    unsigned short wlds[DD * WP];
};

__global__ __launch_bounds__(512) void k_fB(int* __restrict__ binned,
                                            const int* __restrict__ cur,
                                            int* __restrict__ off,
                                            int* __restrict__ cnt,
                                            float* __restrict__ dinv,
                                            const float* __restrict__ x,
                                            const float* __restrict__ W,
                                            unsigned short* __restrict__ hs,
                                            int n, int nbuck, int growoff) {
    __shared__ int hist[512];
    __shared__ int curs[512];
    __shared__ int wsum[8];
    __shared__ UB ub;
    const int t = threadIdx.x;

    if (blockIdx.x < (unsigned)nbuck) {
        const int b = blockIdx.x;
        const int base = b * CAP;
        const int cb = min(cur[b], CAP);     // edges in this bucket
        const int cb4 = cb & ~3;
        const int lane = t & 63, w = t >> 6;

        hist[t] = 0;
        __syncthreads();
        for (int i = t * 4; i < cb4; i += 2048) {
            int4 v4 = *(const int4*)(binned + base + i);
            atomicAdd(&hist[v4.x & 511], 1);
            atomicAdd(&hist[v4.y & 511], 1);
            atomicAdd(&hist[v4.z & 511], 1);
            atomicAdd(&hist[v4.w & 511], 1);
        }
        if (t < cb - cb4)
            atomicAdd(&hist[binned[base + cb4 + t] & 511], 1);
        __syncthreads();
        int v = hist[t];
        int incl = v;
        #pragma unroll
        for (int m = 1; m < 64; m <<= 1) {
            int up = __shfl_up(incl, m);
            if (lane >= m) incl += up;
        }
        if (lane == 63) wsum[w] = incl;
        __syncthreads();
        int wpre = 0;
        #pragma unroll
        for (int j = 0; j < 8; ++j)
            wpre += (j < w) ? wsum[j] : 0;
        int excl = wpre + incl - v;
        curs[t] = excl;
        int d = b * 512 + t;
        if (d < n) {
            off[d]  = base + excl;
            cnt[d]  = v;
            dinv[d] = rsqrtf((float)v + 1.0f);
        }
        __syncthreads();
        for (int i = t * 4; i < cb4; i += 2048) {
            int4 p4 = *(const int4*)(binned + base + i);   // L2-hot re-read
            int p;
            p = atomicAdd(&curs[p4.x & 511], 1); ub.sorted[p] = p4.x >> 9;
            p = atomicAdd(&curs[p4.y & 511], 1); ub.sorted[p] = p4.y >> 9;
            p = atomicAdd(&curs[p4.z & 511], 1); ub.sorted[p] = p4.z >> 9;
            p = atomicAdd(&curs[p4.w & 511], 1); ub.sorted[p] = p4.w >> 9;
        }
        if (t < cb - cb4) {
            int pk = binned[base + cb4 + t];
            int p = atomicAdd(&curs[pk & 511], 1); ub.sorted[p] = pk >> 9;
        }
        __syncthreads();
        for (int i = t * 4; i < cb4; i += 2048)
            *(int4*)(binned + base + i) = *(const int4*)(ub.sorted + i);
        if (t < cb - cb4)
            binned[base + cb4 + t] = ub.sorted[cb4 + t];
        return;
    }

    // ================= gemm role (raw, no dinv), 512 rows/block =================
    for (int i = t; i < DD * DD; i += 512) {
        int k = i >> 7, c = i & 127;
        ub.wlds[c * WP + k] = f2b(W[i]);
    }
    __syncthreads();

    const int gb = blockIdx.x - nbuck;
    const int wave = t >> 6, lane = t & 63;
    const int rowbase = growoff + gb * 512 + wave * 64;
    const int l15 = lane & 15, l4 = lane >> 4;

    bf16x8 a[4][4];
    #pragma unroll
    for (int rb = 0; rb < 4; ++rb) {
        int r = rowbase + rb * 16 + l15;
        int rc = min(r, n - 1);
        const float* xr = x + (size_t)rc * DD;
        #pragma unroll
        for (int kc = 0; kc < 4; ++kc) {
            int k0 = kc * 32 + l4 * 8;
            float4 f0 = *(const float4*)(xr + k0);
            float4 f1 = *(const float4*)(xr + k0 + 4);
            bf16x8 fr;
            fr[0] = (short)f2b(f0.x); fr[1] = (short)f2b(f0.y);
            fr[2] = (short)f2b(f0.z); fr[3] = (short)f2b(f0.w);
            fr[4] = (short)f2b(f1.x); fr[5] = (short)f2b(f1.y);
            fr[6] = (short)f2b(f1.z); fr[7] = (short)f2b(f1.w);
            a[rb][kc] = fr;
        }
    }

    #pragma unroll
    for (int cb8 = 0; cb8 < 8; ++cb8) {
        int c0 = cb8 * 16;
        f32x4 acc[4] = {};
        #pragma unroll
        for (int kc = 0; kc < 4; ++kc) {
            bf16x8 bfrag = *(const bf16x8*)(&ub.wlds[(c0 + l15) * WP + kc * 32 + l4 * 8]);
            #pragma unroll
            for (int rb = 0; rb < 4; ++rb)
                acc[rb] = __builtin_amdgcn_mfma_f32_16x16x32_bf16(a[rb][kc], bfrag, acc[rb], 0, 0, 0);
        }
        #pragma unroll
        for (int rb = 0; rb < 4; ++rb) {
            int r0 = rowbase + rb * 16 + l4 * 4;
            #pragma unroll
            for (int vv = 0; vv < 4; ++vv) {
                int r = r0 + vv;
                if (r < n)
                    hs[(size_t)r * DD + c0 + l15] = f2b(acc[rb][vv]);
            }
        }
    }
}

// ---- out[d] = dinv[d] * ( dinv[d]*h[d] + sum_s dinv[s]*h[s] ) + b
// R4/R7-verbatim (measured 66.6 us; random-gather roofline confirmed across
// 5 rounds / 4 structural variants — FROZEN).
__global__ __launch_bounds__(256, 8) void k_agg(const uint4* __restrict__ hsr,  // hs, row = 16 uint4
                                                const int* __restrict__ ssrc,
                                                const int* __restrict__ off,
                                                const int* __restrict__ cnt,
                                                const float* __restrict__ dinv,
                                                const float* __restrict__ bias,
                                                float* __restrict__ out, int n) {
    const int t = threadIdx.x;
    const int wave = t >> 6, lane = t & 63;
    const int q  = lane >> 4;      // quarter id 0..3
    const int ql = lane & 15;      // lane within quarter; covers bf16 cols [ql*8, ql*8+8)
    const int d = blockIdx.x * 4 + wave;
    if (d >= n) return;

    const int s0 = off[d];
    const int c  = cnt[d];
    const float di = dinv[d];

    float4 accA = {0.f, 0.f, 0.f, 0.f};
    float4 accB = {0.f, 0.f, 0.f, 0.f};

    // self row (independent, issues immediately)
    uint4 vself = hsr[(size_t)d * 16 + ql];

    // batch idx loads: 6 independent broadcast loads (quarter q, round r -> edge r*4+q)
    int idx[6];
    #pragma unroll
    for (int r = 0; r < 6; ++r) {
        int e = r * 4 + q;
        idx[r] = ssrc[s0 + ((e < c) ? e : 0)];   // in-bounds addr even when inactive
    }
    #pragma unroll
    for (int r = 0; r < 6; ++r) {
        int e = r * 4 + q;
        idx[r] = (e < c) ? idx[r] : d;           // inactive slots gather own row (safe)
    }

    // batch gathers: 6 row reads + 6 dinv loads all in flight simultaneously
    uint4 val[6];
    float sc[6];
    #pragma unroll
    for (int r = 0; r < 6; ++r) {
        val[r] = hsr[(size_t)idx[r] * 16 + ql];
        sc[r]  = dinv[idx[r]];
    }

    if (q == 0) bacc16f(accA, accB, vself, di);
    #pragma unroll
    for (int r = 0; r < 6; ++r) {
        int e = r * 4 + q;
        if (e < c) bacc16f(accA, accB, val[r], sc[r]);
    }

    // rare tail: c > 24 (P ~ 2% at mean degree 16)
    for (int i = 24 + q; i < c; i += 4) {
        int s = ssrc[s0 + i];
        uint4 v = hsr[(size_t)s * 16 + ql];
        bacc16f(accA, accB, v, dinv[s]);
    }

    // fold the 4 quarters (bits 4 and 5 of lane id)
    #pragma unroll
    for (int m = 16; m <= 32; m <<= 1) {
        accA.x += __shfl_xor(accA.x, m);
        accA.y += __shfl_xor(accA.y, m);
        accA.z += __shfl_xor(accA.z, m);
        accA.w += __shfl_xor(accA.w, m);
        accB.x += __shfl_xor(accB.x, m);
        accB.y += __shfl_xor(accB.y, m);
        accB.z += __shfl_xor(accB.z, m);
        accB.w += __shfl_xor(accB.w, m);
    }

    if (q == 0) {
        float4 b0 = ((const float4*)bias)[ql * 2];
        float4 b1 = ((const float4*)bias)[ql * 2 + 1];
        float4 o0, o1;
        o0.x = accA.x * di + b0.x;
        o0.y = accA.y * di + b0.y;
        o0.z = accA.z * di + b0.z;
        o0.w = accA.w * di + b0.w;
        o1.x = accB.x * di + b1.x;
        o1.y = accB.y * di + b1.y;
        o1.z = accB.z * di + b1.z;
        o1.w = accB.w * di + b1.w;
        float4* orow = (float4*)(out + (size_t)d * DD);
        orow[ql * 2]     = o0;
        orow[ql * 2 + 1] = o1;
    }
}

extern "C" void kernel_launch(void* const* d_in, const int* in_sizes, int n_in,
                              void* d_out, int out_size, void* d_ws, size_t ws_size,
                              hipStream_t stream) {
    const float* x  = (const float*)d_in[0];
    const int*   ei = (const int*)d_in[1];
    const float* W  = (const float*)d_in[2];
    const float* b  = (const float*)d_in[3];
    float* out = (float*)d_out;

    const int n = in_sizes[0] / DD;      // 100000
    const int E = in_sizes[1] / 2;       // 1600000
    const int* src = ei;
    const int* dst = ei + E;

    const int nbuck = (n + 511) >> 9;    // 196

    unsigned short* hs = (unsigned short*)d_ws;              // n*128 bf16 (25.6 MB)
    int*   binned = (int*)(hs + (size_t)n * DD);             // nbuck*CAP ints (9.6 MB)
    int*   off    = binned + (size_t)nbuck * CAP;            // n ints
    int*   cnt    = off + n;                                 // n ints
    float* dinv   = (float*)(cnt + n);                       // n floats
    int*   cur    = (int*)(dinv + n);                        // nbuck ints

    const int nblkA = 256;
    const int chunk = (((E + nblkA - 1) / nblkA) + 3) & ~3;  // 6252 (mult of 4)

    // gemm rows split across the two fused launches
    const int ngA = 195;                     // rows [0, 49920), 256 rows/block
    const int growoff = ngA * 256;           // 49920
    const int ngB = (n - growoff + 511) / 512;   // 98 blocks, rows [49920, n)

    hipMemsetAsync(cur, 0, (size_t)nbuck * sizeof(int), stream);
    k_fA <<<ngA + nblkA, 256, 0, stream>>>(src, dst, E, chunk, nbuck, cur, binned,
                                           x, W, hs, n, ngA);
    k_fB <<<nbuck + ngB, 512, 0, stream>>>(binned, cur, off, cnt, dinv,
                                           x, W, hs, n, nbuck, growoff);
    k_agg<<<(n + 3) / 4, 256, 0, stream>>>((const uint4*)hs, binned, off, cnt,
                                           dinv, b, out, n);
}

// Round 12
// 115.523 us; speedup vs baseline: 1.0096x; 1.0096x over previous
//
#include <hip/hip_runtime.h>

#define DD 128
#define CAP 12288          // per-bucket slot capacity (mean 8163, +45 sigma)
#define BITER 8            // max pass-1/pass-2 iterations per binA thread

typedef __attribute__((ext_vector_type(8))) short bf16x8;
typedef __attribute__((ext_vector_type(4))) float f32x4;

__device__ inline unsigned short f2b(float f) {
    unsigned int u = __float_as_uint(f);
    u += 0x7fffu + ((u >> 16) & 1u);   // RNE
    return (unsigned short)(u >> 16);
}

// acc += bf16x8(v) * s
__device__ inline void bacc16f(float4& a, float4& b, uint4 v, float s) {
    a.x += __uint_as_float(v.x << 16) * s;
    a.y += __uint_as_float(v.x & 0xffff0000u) * s;
    a.z += __uint_as_float(v.y << 16) * s;
    a.w += __uint_as_float(v.y & 0xffff0000u) * s;
    b.x += __uint_as_float(v.z << 16) * s;
    b.y += __uint_as_float(v.z & 0xffff0000u) * s;
    b.z += __uint_as_float(v.w << 16) * s;
    b.w += __uint_as_float(v.w & 0xffff0000u) * s;
}

// ---- W [k][c] fp32 -> Wt [c][k] bf16 (32 KB, computed ONCE, L2-resident) ----
__global__ __launch_bounds__(256) void k_pre(const float* __restrict__ W,
                                             unsigned short* __restrict__ Wt) {
    int idx = blockIdx.x * 256 + threadIdx.x;
    int k = idx >> 7, c = idx & 127;
    Wt[c * DD + k] = f2b(W[k * DD + c]);
}

// ---- FUSED A: gemm role (blocks 0..ngA-1) + binA role (rest) ----
// binA: two-pass binning; pass 1 loads dst+src as int4 and CACHES the packed
// edge + bucket id in registers, so pass 2 issues ZERO global loads.
// cur starts at 0 (memset); base = t*CAP + reservation (R11-verified).
__global__ __launch_bounds__(256) void k_fA(const int* __restrict__ src,
                                            const int* __restrict__ dst, int E,
                                            int chunk, int nbuck,
                                            int* __restrict__ cur,
                                            int* __restrict__ binned,
                                            const float* __restrict__ x,
                                            const unsigned short* __restrict__ Wt,
                                            unsigned short* __restrict__ hs,
                                            int n, int ngA) {
    const int t = threadIdx.x;
    if ((int)blockIdx.x >= ngA) {
        __shared__ int hist[256];
        __shared__ int base[256];
        __shared__ int curs[256];
        const int e0 = (blockIdx.x - ngA) * chunk;
        const int e1 = min(e0 + chunk, E);   // span is a multiple of 4 (E%4==0)

        hist[t] = 0; curs[t] = 0;
        __syncthreads();
        int4 pk4[BITER];   // packed (src<<9)|(dst&511)
        int  bb4[BITER];   // 4 bucket ids (8b each; nbuck=196<256)
        #pragma unroll
        for (int i = 0; i < BITER; ++i) {
            int e = e0 + t * 4 + i * 1024;
            if (e < e1) {
                int4 d4 = *(const int4*)(dst + e);
                int4 s4 = *(const int4*)(src + e);
                atomicAdd(&hist[d4.x >> 9], 1);
                atomicAdd(&hist[d4.y >> 9], 1);
                atomicAdd(&hist[d4.z >> 9], 1);
                atomicAdd(&hist[d4.w >> 9], 1);
                pk4[i].x = (s4.x << 9) | (d4.x & 511);
                pk4[i].y = (s4.y << 9) | (d4.y & 511);
                pk4[i].z = (s4.z << 9) | (d4.z & 511);
                pk4[i].w = (s4.w << 9) | (d4.w & 511);
                bb4[i] = (d4.x >> 9) | ((d4.y >> 9) << 8)
                       | ((d4.z >> 9) << 16) | ((d4.w >> 9) << 24);
            }
        }
        __syncthreads();
        if (t < nbuck && hist[t] > 0)
            base[t] = t * CAP + atomicAdd(&cur[t], hist[t]);
        __syncthreads();
        #pragma unroll
        for (int i = 0; i < BITER; ++i) {
            int e = e0 + t * 4 + i * 1024;
            if (e < e1) {
                int b, p, idx;
                b = bb4[i] & 255;
                p = atomicAdd(&curs[b], 1); idx = base[b] + p;
                if (idx < (b + 1) * CAP) binned[idx] = pk4[i].x;
                b = (bb4[i] >> 8) & 255;
                p = atomicAdd(&curs[b], 1); idx = base[b] + p;
                if (idx < (b + 1) * CAP) binned[idx] = pk4[i].y;
                b = (bb4[i] >> 16) & 255;
                p = atomicAdd(&curs[b], 1); idx = base[b] + p;
                if (idx < (b + 1) * CAP) binned[idx] = pk4[i].z;
                b = (bb4[i] >> 24) & 255;
                p = atomicAdd(&curs[b], 1); idx = base[b] + p;
                if (idx < (b + 1) * CAP) binned[idx] = pk4[i].w;
            }
        }
        return;
    }

    // ================= gemm role (raw, no dinv) — R10-verbatim =================
    const int wave = t >> 6, lane = t & 63;
    const int rowbase = blockIdx.x * 256 + wave * 64;
    const int l15 = lane & 15, l4 = lane >> 4;

    bf16x8 a[4][4];
    #pragma unroll
    for (int rb = 0; rb < 4; ++rb) {
        int r = rowbase + rb * 16 + l15;
        int rc = min(r, n - 1);
        const float* xr = x + (size_t)rc * DD;
        #pragma unroll
        for (int kc = 0; kc < 4; ++kc) {
            int k0 = kc * 32 + l4 * 8;
            float4 f0 = *(const float4*)(xr + k0);
            float4 f1 = *(const float4*)(xr + k0 + 4);
            bf16x8 fr;
            fr[0] = (short)f2b(f0.x); fr[1] = (short)f2b(f0.y);
            fr[2] = (short)f2b(f0.z); fr[3] = (short)f2b(f0.w);
            fr[4] = (short)f2b(f1.x); fr[5] = (short)f2b(f1.y);
            fr[6] = (short)f2b(f1.z); fr[7] = (short)f2b(f1.w);
            a[rb][kc] = fr;
        }
    }

    #pragma unroll
    for (int cb = 0; cb < 8; ++cb) {
        int c0 = cb * 16;
        f32x4 acc[4] = {};
        #pragma unroll
        for (int kc = 0; kc < 4; ++kc) {
            bf16x8 bfrag = *(const bf16x8*)(Wt + (size_t)(c0 + l15) * DD + kc * 32 + l4 * 8);
            #pragma unroll
            for (int rb = 0; rb < 4; ++rb)
                acc[rb] = __builtin_amdgcn_mfma_f32_16x16x32_bf16(a[rb][kc], bfrag, acc[rb], 0, 0, 0);
        }
        #pragma unroll
        for (int rb = 0; rb < 4; ++rb) {
            int r0 = rowbase + rb * 16 + l4 * 4;
            #pragma unroll
            for (int vv = 0; vv < 4; ++vv) {
                int r = r0 + vv;
                if (r < n)
                    hs[(size_t)r * DD + c0 + l15] = f2b(acc[rb][vv]);
            }
        }
    }
}

// ---- FUSED B: binB role (blocks 0..nbuck-1) + gemm role (rest) ----
// R10-verbatim except cb = min(cur[b], CAP) (cur holds counts now).
__global__ __launch_bounds__(512) void k_fB(int* __restrict__ binned,
                                            const int* __restrict__ cur,
                                            int* __restrict__ off,
                                            int* __restrict__ cnt,
                                            float* __restrict__ dinv,
                                            const float* __restrict__ x,
                                            const unsigned short* __restrict__ Wt,
                                            unsigned short* __restrict__ hs,
                                            int n, int nbuck, int growoff) {
    __shared__ int hist[512];
    __shared__ int curs[512];
    __shared__ int wsum[8];
    __shared__ int sorted[CAP];
    const int t = threadIdx.x;

    if (blockIdx.x < (unsigned)nbuck) {
        const int b = blockIdx.x;
        const int base = b * CAP;
        const int cb = min(cur[b], CAP);     // edges in this bucket
        const int cb4 = cb & ~3;
        const int lane = t & 63, w = t >> 6;

        hist[t] = 0;
        __syncthreads();
        for (int i = t * 4; i < cb4; i += 2048) {
            int4 v4 = *(const int4*)(binned + base + i);
            atomicAdd(&hist[v4.x & 511], 1);
            atomicAdd(&hist[v4.y & 511], 1);
            atomicAdd(&hist[v4.z & 511], 1);
            atomicAdd(&hist[v4.w & 511], 1);
        }
        if (t < cb - cb4)
            atomicAdd(&hist[binned[base + cb4 + t] & 511], 1);
        __syncthreads();
        int v = hist[t];
        int incl = v;
        #pragma unroll
        for (int m = 1; m < 64; m <<= 1) {
            int up = __shfl_up(incl, m);
            if (lane >= m) incl += up;
        }
        if (lane == 63) wsum[w] = incl;
        __syncthreads();
        int wpre = 0;
        #pragma unroll
        for (int j = 0; j < 8; ++j)
            wpre += (j < w) ? wsum[j] : 0;
        int excl = wpre + incl - v;
        curs[t] = excl;
        int d = b * 512 + t;
        if (d < n) {
            off[d]  = base + excl;
            cnt[d]  = v;
            dinv[d] = rsqrtf((float)v + 1.0f);
        }
        __syncthreads();
        for (int i = t * 4; i < cb4; i += 2048) {
            int4 p4 = *(const int4*)(binned + base + i);   // L2-hot re-read
            int p;
            p = atomicAdd(&curs[p4.x & 511], 1); sorted[p] = p4.x >> 9;
            p = atomicAdd(&curs[p4.y & 511], 1); sorted[p] = p4.y >> 9;
            p = atomicAdd(&curs[p4.z & 511], 1); sorted[p] = p4.z >> 9;
            p = atomicAdd(&curs[p4.w & 511], 1); sorted[p] = p4.w >> 9;
        }
        if (t < cb - cb4) {
            int pk = binned[base + cb4 + t];
            int p = atomicAdd(&curs[pk & 511], 1); sorted[p] = pk >> 9;
        }
        __syncthreads();
        for (int i = t * 4; i < cb4; i += 2048)
            *(int4*)(binned + base + i) = *(const int4*)(sorted + i);
        if (t < cb - cb4)
            binned[base + cb4 + t] = sorted[cb4 + t];
        return;
    }

    // ================= gemm role (raw, no dinv) — R10-verbatim =================
    const int gb = blockIdx.x - nbuck;
    const int wave = t >> 6, lane = t & 63;
    const int rowbase = growoff + gb * 256 + wave * 32;
    const int l15 = lane & 15, l4 = lane >> 4;

    bf16x8 a[2][4];
    #pragma unroll
    for (int rb = 0; rb < 2; ++rb) {
        int r = rowbase + rb * 16 + l15;
        int rc = min(r, n - 1);
        const float* xr = x + (size_t)rc * DD;
        #pragma unroll
        for (int kc = 0; kc < 4; ++kc) {
            int k0 = kc * 32 + l4 * 8;
            float4 f0 = *(const float4*)(xr + k0);
            float4 f1 = *(const float4*)(xr + k0 + 4);
            bf16x8 fr;
            fr[0] = (short)f2b(f0.x); fr[1] = (short)f2b(f0.y);
            fr[2] = (short)f2b(f0.z); fr[3] = (short)f2b(f0.w);
            fr[4] = (short)f2b(f1.x); fr[5] = (short)f2b(f1.y);
            fr[6] = (short)f2b(f1.z); fr[7] = (short)f2b(f1.w);
            a[rb][kc] = fr;
        }
    }

    #pragma unroll
    for (int cb8 = 0; cb8 < 8; ++cb8) {
        int c0 = cb8 * 16;
        f32x4 acc[2] = {};
        #pragma unroll
        for (int kc = 0; kc < 4; ++kc) {
            bf16x8 bfrag = *(const bf16x8*)(Wt + (size_t)(c0 + l15) * DD + kc * 32 + l4 * 8);
            #pragma unroll
            for (int rb = 0; rb < 2; ++rb)
                acc[rb] = __builtin_amdgcn_mfma_f32_16x16x32_bf16(a[rb][kc], bfrag, acc[rb], 0, 0, 0);
        }
        #pragma unroll
        for (int rb = 0; rb < 2; ++rb) {
            int r0 = rowbase + rb * 16 + l4 * 4;
            #pragma unroll
            for (int vv = 0; vv < 4; ++vv) {
                int r = r0 + vv;
                if (r < n)
                    hs[(size_t)r * DD + c0 + l15] = f2b(acc[rb][vv]);
            }
        }
    }
}

// ---- out[d] = dinv[d] * ( dinv[d]*h[d] + sum_s dinv[s]*h[s] ) + b
// R4/R7-verbatim (66.4-66.8 us across 6 rounds; random-gather roofline — FROZEN).
__global__ __launch_bounds__(256, 8) void k_agg(const uint4* __restrict__ hsr,  // hs, row = 16 uint4
                                                const int* __restrict__ ssrc,
                                                const int* __restrict__ off,
                                                const int* __restrict__ cnt,
                                                const float* __restrict__ dinv,
                                                const float* __restrict__ bias,
                                                float* __restrict__ out, int n) {
    const int t = threadIdx.x;
    const int wave = t >> 6, lane = t & 63;
    const int q  = lane >> 4;      // quarter id 0..3
    const int ql = lane & 15;      // lane within quarter; covers bf16 cols [ql*8, ql*8+8)
    const int d = blockIdx.x * 4 + wave;
    if (d >= n) return;

    const int s0 = off[d];
    const int c  = cnt[d];
    const float di = dinv[d];

    float4 accA = {0.f, 0.f, 0.f, 0.f};
    float4 accB = {0.f, 0.f, 0.f, 0.f};

    // self row (independent, issues immediately)
    uint4 vself = hsr[(size_t)d * 16 + ql];

    // batch idx loads: 6 independent broadcast loads (quarter q, round r -> edge r*4+q)
    int idx[6];
    #pragma unroll
    for (int r = 0; r < 6; ++r) {
        int e = r * 4 + q;
        idx[r] = ssrc[s0 + ((e < c) ? e : 0)];   // in-bounds addr even when inactive
    }
    #pragma unroll
    for (int r = 0; r < 6; ++r) {
        int e = r * 4 + q;
        idx[r] = (e < c) ? idx[r] : d;           // inactive slots gather own row (safe)
    }

    // batch gathers: 6 row reads + 6 dinv loads all in flight simultaneously
    uint4 val[6];
    float sc[6];
    #pragma unroll
    for (int r = 0; r < 6; ++r) {
        val[r] = hsr[(size_t)idx[r] * 16 + ql];
        sc[r]  = dinv[idx[r]];
    }

    if (q == 0) bacc16f(accA, accB, vself, di);
    #pragma unroll
    for (int r = 0; r < 6; ++r) {
        int e = r * 4 + q;
        if (e < c) bacc16f(accA, accB, val[r], sc[r]);
    }

    // rare tail: c > 24 (P ~ 2% at mean degree 16)
    for (int i = 24 + q; i < c; i += 4) {
        int s = ssrc[s0 + i];
        uint4 v = hsr[(size_t)s * 16 + ql];
        bacc16f(accA, accB, v, dinv[s]);
    }

    // fold the 4 quarters (bits 4 and 5 of lane id)
    #pragma unroll
    for (int m = 16; m <= 32; m <<= 1) {
        accA.x += __shfl_xor(accA.x, m);
        accA.y += __shfl_xor(accA.y, m);
        accA.z += __shfl_xor(accA.z, m);
        accA.w += __shfl_xor(accA.w, m);
        accB.x += __shfl_xor(accB.x, m);
        accB.y += __shfl_xor(accB.y, m);
        accB.z += __shfl_xor(accB.z, m);
        accB.w += __shfl_xor(accB.w, m);
    }

    if (q == 0) {
        float4 b0 = ((const float4*)bias)[ql * 2];
        float4 b1 = ((const float4*)bias)[ql * 2 + 1];
        float4 o0, o1;
        o0.x = accA.x * di + b0.x;
        o0.y = accA.y * di + b0.y;
        o0.z = accA.z * di + b0.z;
        o0.w = accA.w * di + b0.w;
        o1.x = accB.x * di + b1.x;
        o1.y = accB.y * di + b1.y;
        o1.z = accB.z * di + b1.z;
        o1.w = accB.w * di + b1.w;
        float4* orow = (float4*)(out + (size_t)d * DD);
        orow[ql * 2]     = o0;
        orow[ql * 2 + 1] = o1;
    }
}

extern "C" void kernel_launch(void* const* d_in, const int* in_sizes, int n_in,
                              void* d_out, int out_size, void* d_ws, size_t ws_size,
                              hipStream_t stream) {
    const float* x  = (const float*)d_in[0];
    const int*   ei = (const int*)d_in[1];
    const float* W  = (const float*)d_in[2];
    const float* b  = (const float*)d_in[3];
    float* out = (float*)d_out;

    const int n = in_sizes[0] / DD;      // 100000
    const int E = in_sizes[1] / 2;       // 1600000
    const int* src = ei;
    const int* dst = ei + E;

    const int nbuck = (n + 511) >> 9;    // 196

    unsigned short* hs = (unsigned short*)d_ws;              // n*128 bf16 (25.6 MB)
    unsigned short* Wt = hs + (size_t)n * DD;                // 16384 bf16
    int*   binned = (int*)(Wt + DD * DD);                    // nbuck*CAP ints (9.6 MB)
    int*   off    = binned + (size_t)nbuck * CAP;            // n ints
    int*   cnt    = off + n;                                 // n ints
    float* dinv   = (float*)(cnt + n);                       // n floats
    int*   cur    = (int*)(dinv + n);                        // nbuck ints

    const int nblkA = 256;
    const int chunk = (((E + nblkA - 1) / nblkA) + 3) & ~3;  // 6252 (mult of 4; <= BITER*1024)

    // gemm rows split across the two fused launches
    const int ngA = 195;                     // rows [0, 49920), 256 rows/block
    const int growoff = ngA * 256;           // 49920
    const int ngB = (n - growoff + 255) / 256;   // 196 blocks, rows [49920, n)

    hipMemsetAsync(cur, 0, (size_t)nbuck * sizeof(int), stream);
    k_pre<<<DD * DD / 256, 256, 0, stream>>>(W, Wt);
    k_fA <<<ngA + nblkA, 256, 0, stream>>>(src, dst, E, chunk, nbuck, cur, binned,
                                           x, Wt, hs, n, ngA);
    k_fB <<<nbuck + ngB, 512, 0, stream>>>(binned, cur, off, cnt, dinv,
                                           x, Wt, hs, n, nbuck, growoff);
    k_agg<<<(n + 3) / 4, 256, 0, stream>>>((const uint4*)hs, binned, off, cnt,
                                           dinv, b, out, n);
}

// Round 13
// 111.834 us; speedup vs baseline: 1.0429x; 1.0330x over previous
//
#include <hip/hip_runtime.h>

#define DD 128
#define CAP 12288          // per-bucket slot capacity (mean 8163, +45 sigma)

typedef __attribute__((ext_vector_type(8))) short bf16x8;
typedef __attribute__((ext_vector_type(4))) float f32x4;

__device__ inline unsigned short f2b(float f) {
    unsigned int u = __float_as_uint(f);
    u += 0x7fffu + ((u >> 16) & 1u);   // RNE
    return (unsigned short)(u >> 16);
}

// acc += bf16x8(v) * s
__device__ inline void bacc16f(float4& a, float4& b, uint4 v, float s) {
    a.x += __uint_as_float(v.x << 16) * s;
    a.y += __uint_as_float(v.x & 0xffff0000u) * s;
    a.z += __uint_as_float(v.y << 16) * s;
    a.w += __uint_as_float(v.y & 0xffff0000u) * s;
    b.x += __uint_as_float(v.z << 16) * s;
    b.y += __uint_as_float(v.z & 0xffff0000u) * s;
    b.z += __uint_as_float(v.w << 16) * s;
    b.w += __uint_as_float(v.w & 0xffff0000u) * s;
}

// ---- merged: W transpose->bf16 (blocks 0..63) + cursor init (block 64+) ----
__global__ __launch_bounds__(256) void k_pre(const float* __restrict__ W,
                                             unsigned short* __restrict__ Wt,
                                             int* __restrict__ cur, int nbuck) {
    int bid = blockIdx.x;
    if (bid < 64) {
        int idx = bid * 256 + threadIdx.x;
        int k = idx >> 7, c = idx & 127;
        Wt[c * DD + k] = f2b(W[k * DD + c]);
    } else {
        int b = (bid - 64) * 256 + threadIdx.x;
        if (b < nbuck) cur[b] = b * CAP;
    }
}

// ---- FUSED A: gemm role FIRST (blocks 0..ngA-1), binA role after ----
// binA: R7 structure, loads vectorized to int4 (4 edges/lane, 16B/lane);
// chunk is a multiple of 4 so every int4 access is 16B-aligned.
__global__ __launch_bounds__(256) void k_fA(const int* __restrict__ src,
                                            const int* __restrict__ dst, int E,
                                            int chunk, int nbuck,
                                            int* __restrict__ cur,
                                            int* __restrict__ binned,
                                            const float* __restrict__ x,
                                            const unsigned short* __restrict__ Wt,
                                            unsigned short* __restrict__ hs,
                                            int n, int ngA) {
    const int t = threadIdx.x;
    if ((int)blockIdx.x >= ngA) {
        __shared__ int hist[256];
        __shared__ int base[256];
        __shared__ int curs[256];
        const int e0 = (blockIdx.x - ngA) * chunk;
        const int e1 = min(e0 + chunk, E);   // span is a multiple of 4 (E%4==0)

        if (t < 256) { hist[t] = 0; curs[t] = 0; }
        __syncthreads();
        for (int e = e0 + t * 4; e < e1; e += 1024) {
            int4 d4 = *(const int4*)(dst + e);
            atomicAdd(&hist[d4.x >> 9], 1);
            atomicAdd(&hist[d4.y >> 9], 1);
            atomicAdd(&hist[d4.z >> 9], 1);
            atomicAdd(&hist[d4.w >> 9], 1);
        }
        __syncthreads();
        if (t < nbuck && hist[t] > 0)
            base[t] = atomicAdd(&cur[t], hist[t]);
        __syncthreads();
        for (int e = e0 + t * 4; e < e1; e += 1024) {
            int4 d4 = *(const int4*)(dst + e);
            int4 s4 = *(const int4*)(src + e);
            {
                int b = d4.x >> 9, p = atomicAdd(&curs[b], 1), idx = base[b] + p;
                if (idx < (b + 1) * CAP) binned[idx] = (s4.x << 9) | (d4.x & 511);
            }
            {
                int b = d4.y >> 9, p = atomicAdd(&curs[b], 1), idx = base[b] + p;
                if (idx < (b + 1) * CAP) binned[idx] = (s4.y << 9) | (d4.y & 511);
            }
            {
                int b = d4.z >> 9, p = atomicAdd(&curs[b], 1), idx = base[b] + p;
                if (idx < (b + 1) * CAP) binned[idx] = (s4.z << 9) | (d4.z & 511);
            }
            {
                int b = d4.w >> 9, p = atomicAdd(&curs[b], 1), idx = base[b] + p;
                if (idx < (b + 1) * CAP) binned[idx] = (s4.w << 9) | (d4.w & 511);
            }
        }
        return;
    }

    // ================= gemm role (raw, no dinv) — R7-verbatim =================
    const int wave = t >> 6, lane = t & 63;
    const int rowbase = blockIdx.x * 256 + wave * 64;
    const int l15 = lane & 15, l4 = lane >> 4;

    bf16x8 a[4][4];
    #pragma unroll
    for (int rb = 0; rb < 4; ++rb) {
        int r = rowbase + rb * 16 + l15;
        int rc = min(r, n - 1);
        const float* xr = x + (size_t)rc * DD;
        #pragma unroll
        for (int kc = 0; kc < 4; ++kc) {
            int k0 = kc * 32 + l4 * 8;
            float4 f0 = *(const float4*)(xr + k0);
            float4 f1 = *(const float4*)(xr + k0 + 4);
            bf16x8 fr;
            fr[0] = (short)f2b(f0.x); fr[1] = (short)f2b(f0.y);
            fr[2] = (short)f2b(f0.z); fr[3] = (short)f2b(f0.w);
            fr[4] = (short)f2b(f1.x); fr[5] = (short)f2b(f1.y);
            fr[6] = (short)f2b(f1.z); fr[7] = (short)f2b(f1.w);
            a[rb][kc] = fr;
        }
    }

    #pragma unroll
    for (int cb = 0; cb < 8; ++cb) {
        int c0 = cb * 16;
        f32x4 acc[4] = {};
        #pragma unroll
        for (int kc = 0; kc < 4; ++kc) {
            bf16x8 bfrag = *(const bf16x8*)(Wt + (size_t)(c0 + l15) * DD + kc * 32 + l4 * 8);
            #pragma unroll
            for (int rb = 0; rb < 4; ++rb)
                acc[rb] = __builtin_amdgcn_mfma_f32_16x16x32_bf16(a[rb][kc], bfrag, acc[rb], 0, 0, 0);
        }
        #pragma unroll
        for (int rb = 0; rb < 4; ++rb) {
            int r0 = rowbase + rb * 16 + l4 * 4;
            #pragma unroll
            for (int vv = 0; vv < 4; ++vv) {
                int r = r0 + vv;
                if (r < n)
                    hs[(size_t)r * DD + c0 + l15] = f2b(acc[rb][vv]);
            }
        }
    }
}

// ---- FUSED B: binB role (blocks 0..nbuck-1) + gemm role (rest) ----
// binB: R7's 3-pass structure (hist from global; scatter -> LDS sorted from
// L2-hot re-read; DENSE int4 writeback). Shfl scan (4 barriers).
__global__ __launch_bounds__(512) void k_fB(int* __restrict__ binned,
                                            const int* __restrict__ cur,
                                            int* __restrict__ off,
                                            int* __restrict__ cnt,
                                            float* __restrict__ dinv,
                                            const float* __restrict__ x,
                                            const unsigned short* __restrict__ Wt,
                                            unsigned short* __restrict__ hs,
                                            int n, int nbuck, int growoff) {
    __shared__ int hist[512];
    __shared__ int curs[512];
    __shared__ int wsum[8];
    __shared__ int sorted[CAP];
    const int t = threadIdx.x;

    if (blockIdx.x < (unsigned)nbuck) {
        const int b = blockIdx.x;
        const int base = b * CAP;
        const int cb = cur[b] - base;        // edges in this bucket
        const int cb4 = cb & ~3;
        const int lane = t & 63, w = t >> 6;

        hist[t] = 0;
        __syncthreads();
        for (int i = t * 4; i < cb4; i += 2048) {
            int4 v4 = *(const int4*)(binned + base + i);
            atomicAdd(&hist[v4.x & 511], 1);
            atomicAdd(&hist[v4.y & 511], 1);
            atomicAdd(&hist[v4.z & 511], 1);
            atomicAdd(&hist[v4.w & 511], 1);
        }
        if (t < cb - cb4)
            atomicAdd(&hist[binned[base + cb4 + t] & 511], 1);
        __syncthreads();
        int v = hist[t];
        int incl = v;
        #pragma unroll
        for (int m = 1; m < 64; m <<= 1) {
            int up = __shfl_up(incl, m);
            if (lane >= m) incl += up;
        }
        if (lane == 63) wsum[w] = incl;
        __syncthreads();
        int wpre = 0;
        #pragma unroll
        for (int j = 0; j < 8; ++j)
            wpre += (j < w) ? wsum[j] : 0;
        int excl = wpre + incl - v;
        curs[t] = excl;
        int d = b * 512 + t;
        if (d < n) {
            off[d]  = base + excl;
            cnt[d]  = v;
            dinv[d] = rsqrtf((float)v + 1.0f);
        }
        __syncthreads();
        for (int i = t * 4; i < cb4; i += 2048) {
            int4 p4 = *(const int4*)(binned + base + i);   // L2-hot re-read
            int p;
            p = atomicAdd(&curs[p4.x & 511], 1); sorted[p] = p4.x >> 9;
            p = atomicAdd(&curs[p4.y & 511], 1); sorted[p] = p4.y >> 9;
            p = atomicAdd(&curs[p4.z & 511], 1); sorted[p] = p4.z >> 9;
            p = atomicAdd(&curs[p4.w & 511], 1); sorted[p] = p4.w >> 9;
        }
        if (t < cb - cb4) {
            int pk = binned[base + cb4 + t];
            int p = atomicAdd(&curs[pk & 511], 1); sorted[p] = pk >> 9;
        }
        __syncthreads();
        for (int i = t * 4; i < cb4; i += 2048)
            *(int4*)(binned + base + i) = *(const int4*)(sorted + i);
        if (t < cb - cb4)
            binned[base + cb4 + t] = sorted[cb4 + t];
        return;
    }

    // ================= gemm role (raw, no dinv) — R7-verbatim =================
    const int gb = blockIdx.x - nbuck;
    const int wave = t >> 6, lane = t & 63;
    const int rowbase = growoff + gb * 256 + wave * 32;
    const int l15 = lane & 15, l4 = lane >> 4;

    bf16x8 a[2][4];
    #pragma unroll
    for (int rb = 0; rb < 2; ++rb) {
        int r = rowbase + rb * 16 + l15;
        int rc = min(r, n - 1);
        const float* xr = x + (size_t)rc * DD;
        #pragma unroll
        for (int kc = 0; kc < 4; ++kc) {
            int k0 = kc * 32 + l4 * 8;
            float4 f0 = *(const float4*)(xr + k0);
            float4 f1 = *(const float4*)(xr + k0 + 4);
            bf16x8 fr;
            fr[0] = (short)f2b(f0.x); fr[1] = (short)f2b(f0.y);
            fr[2] = (short)f2b(f0.z); fr[3] = (short)f2b(f0.w);
            fr[4] = (short)f2b(f1.x); fr[5] = (short)f2b(f1.y);
            fr[6] = (short)f2b(f1.z); fr[7] = (short)f2b(f1.w);
            a[rb][kc] = fr;
        }
    }

    #pragma unroll
    for (int cb8 = 0; cb8 < 8; ++cb8) {
        int c0 = cb8 * 16;
        f32x4 acc[2] = {};
        #pragma unroll
        for (int kc = 0; kc < 4; ++kc) {
            bf16x8 bfrag = *(const bf16x8*)(Wt + (size_t)(c0 + l15) * DD + kc * 32 + l4 * 8);
            #pragma unroll
            for (int rb = 0; rb < 2; ++rb)
                acc[rb] = __builtin_amdgcn_mfma_f32_16x16x32_bf16(a[rb][kc], bfrag, acc[rb], 0, 0, 0);
        }
        #pragma unroll
        for (int rb = 0; rb < 2; ++rb) {
            int r0 = rowbase + rb * 16 + l4 * 4;
            #pragma unroll
            for (int vv = 0; vv < 4; ++vv) {
                int r = r0 + vv;
                if (r < n)
                    hs[(size_t)r * DD + c0 + l15] = f2b(acc[rb][vv]);
            }
        }
    }
}

// ---- out[d] = dinv[d] * ( dinv[d]*h[d] + sum_s dinv[s]*h[s] ) + b
// R4/R7-verbatim (65.9-66.8 us across 7 rounds; random-gather roofline — FROZEN).
__global__ __launch_bounds__(256, 8) void k_agg(const uint4* __restrict__ hsr,  // hs, row = 16 uint4
                                                const int* __restrict__ ssrc,
                                                const int* __restrict__ off,
                                                const int* __restrict__ cnt,
                                                const float* __restrict__ dinv,
                                                const float* __restrict__ bias,
                                                float* __restrict__ out, int n) {
    const int t = threadIdx.x;
    const int wave = t >> 6, lane = t & 63;
    const int q  = lane >> 4;      // quarter id 0..3
    const int ql = lane & 15;      // lane within quarter; covers bf16 cols [ql*8, ql*8+8)
    const int d = blockIdx.x * 4 + wave;
    if (d >= n) return;

    const int s0 = off[d];
    const int c  = cnt[d];
    const float di = dinv[d];

    float4 accA = {0.f, 0.f, 0.f, 0.f};
    float4 accB = {0.f, 0.f, 0.f, 0.f};

    // self row (independent, issues immediately)
    uint4 vself = hsr[(size_t)d * 16 + ql];

    // batch idx loads: 6 independent broadcast loads (quarter q, round r -> edge r*4+q)
    int idx[6];
    #pragma unroll
    for (int r = 0; r < 6; ++r) {
        int e = r * 4 + q;
        idx[r] = ssrc[s0 + ((e < c) ? e : 0)];   // in-bounds addr even when inactive
    }
    #pragma unroll
    for (int r = 0; r < 6; ++r) {
        int e = r * 4 + q;
        idx[r] = (e < c) ? idx[r] : d;           // inactive slots gather own row (safe)
    }

    // batch gathers: 6 row reads + 6 dinv loads all in flight simultaneously
    uint4 val[6];
    float sc[6];
    #pragma unroll
    for (int r = 0; r < 6; ++r) {
        val[r] = hsr[(size_t)idx[r] * 16 + ql];
        sc[r]  = dinv[idx[r]];
    }

    if (q == 0) bacc16f(accA, accB, vself, di);
    #pragma unroll
    for (int r = 0; r < 6; ++r) {
        int e = r * 4 + q;
        if (e < c) bacc16f(accA, accB, val[r], sc[r]);
    }

    // rare tail: c > 24 (P ~ 2% at mean degree 16)
    for (int i = 24 + q; i < c; i += 4) {
        int s = ssrc[s0 + i];
        uint4 v = hsr[(size_t)s * 16 + ql];
        bacc16f(accA, accB, v, dinv[s]);
    }

    // fold the 4 quarters (bits 4 and 5 of lane id)
    #pragma unroll
    for (int m = 16; m <= 32; m <<= 1) {
        accA.x += __shfl_xor(accA.x, m);
        accA.y += __shfl_xor(accA.y, m);
        accA.z += __shfl_xor(accA.z, m);
        accA.w += __shfl_xor(accA.w, m);
        accB.x += __shfl_xor(accB.x, m);
        accB.y += __shfl_xor(accB.y, m);
        accB.z += __shfl_xor(accB.z, m);
        accB.w += __shfl_xor(accB.w, m);
    }

    if (q == 0) {
        float4 b0 = ((const float4*)bias)[ql * 2];
        float4 b1 = ((const float4*)bias)[ql * 2 + 1];
        float4 o0, o1;
        o0.x = accA.x * di + b0.x;
        o0.y = accA.y * di + b0.y;
        o0.z = accA.z * di + b0.z;
        o0.w = accA.w * di + b0.w;
        o1.x = accB.x * di + b1.x;
        o1.y = accB.y * di + b1.y;
        o1.z = accB.z * di + b1.z;
        o1.w = accB.w * di + b1.w;
        float4* orow = (float4*)(out + (size_t)d * DD);
        orow[ql * 2]     = o0;
        orow[ql * 2 + 1] = o1;
    }
}

extern "C" void kernel_launch(void* const* d_in, const int* in_sizes, int n_in,
                              void* d_out, int out_size, void* d_ws, size_t ws_size,
                              hipStream_t stream) {
    const float* x  = (const float*)d_in[0];
    const int*   ei = (const int*)d_in[1];
    const float* W  = (const float*)d_in[2];
    const float* b  = (const float*)d_in[3];
    float* out = (float*)d_out;

    const int n = in_sizes[0] / DD;      // 100000
    const int E = in_sizes[1] / 2;       // 1600000
    const int* src = ei;
    const int* dst = ei + E;

    const int nbuck = (n + 511) >> 9;    // 196

    unsigned short* hs = (unsigned short*)d_ws;              // n*128 bf16 (25.6 MB)
    unsigned short* Wt = hs + (size_t)n * DD;                // 16384 bf16
    int*   binned = (int*)(Wt + DD * DD);                    // nbuck*CAP ints (9.6 MB)
    int*   off    = binned + (size_t)nbuck * CAP;            // n ints
    int*   cnt    = off + n;                                 // n ints
    float* dinv   = (float*)(cnt + n);                       // n floats
    int*   cur    = (int*)(dinv + n);                        // nbuck ints

    const int nblkA = 256;
    const int chunk = (((E + nblkA - 1) / nblkA) + 3) & ~3;  // 6252 (mult of 4)

    // gemm rows split across the two fused launches
    const int ngA = 195;                     // rows [0, 49920), 256 rows/block
    const int growoff = ngA * 256;           // 49920
    const int ngB = (n - growoff + 255) / 256;   // 196 blocks, rows [49920, n)

    k_pre<<<64 + (nbuck + 255) / 256, 256, 0, stream>>>(W, Wt, cur, nbuck);
    k_fA <<<ngA + nblkA, 256, 0, stream>>>(src, dst, E, chunk, nbuck, cur, binned,
                                           x, Wt, hs, n, ngA);
    k_fB <<<nbuck + ngB, 512, 0, stream>>>(binned, cur, off, cnt, dinv,
                                           x, Wt, hs, n, nbuck, growoff);
    k_agg<<<(n + 3) / 4, 256, 0, stream>>>((const uint4*)hs, binned, off, cnt,
                                           dinv, b, out, n);
}